// Round 11
// baseline (1560.643 us; speedup 1.0000x reference)
//
#include <hip/hip_runtime.h>

#define B 2
#define NQ 4096
#define NA 2048
#define CH 1024  // attention chunk (8 chunks)
#define LDK 40   // LDS row stride (shorts)

typedef __attribute__((ext_vector_type(8))) short bf16x8;
typedef __attribute__((ext_vector_type(4))) float f32x4;

__device__ __forceinline__ float b2f(unsigned short u){ union{unsigned i; float f;} c; c.i=((unsigned)u)<<16; return c.f; }
__device__ __forceinline__ unsigned short f2b(float f){ union{float f; unsigned u;} c; c.f=f; unsigned u=c.u; u += 0x7FFFu + ((u>>16)&1u); return (unsigned short)(u>>16); }
__device__ __forceinline__ void split2(float x, short& h, short& l){
    unsigned short hh = f2b(x); h = (short)hh; l = (short)f2b(x - b2f(hh));
}
__device__ __forceinline__ float4 ld4(const float* p){ return *(const float4*)p; }

// ======================= small projections =======================
__global__ __launch_bounds__(256) void proj_small(
    const float* __restrict__ gf,
    const float* __restrict__ w_qs, const float* __restrict__ w_kg, const float* __restrict__ w_vg,
    float* __restrict__ q_attn, float* __restrict__ kgv, float* __restrict__ vgv)
{
    int mat = blockIdx.x >> 1, b = blockIdx.x & 1;
    const float* W = (mat==0) ? w_qs : (mat==1 ? w_kg : w_vg);
    float* O       = (mat==0) ? q_attn : (mat==1 ? kgv : vgv);
    __shared__ float sg[512];
    int t = threadIdx.x;
    for (int i=t;i<512;i+=256) sg[i] = gf[b*512+i];
    __syncthreads();
    for (int c=t;c<512;c+=256) {
        float acc = 0.f;
        for (int k=0;k<512;k++) acc = fmaf(sg[k], W[k*512+c], acc);
        O[b*512+c] = acc;
    }
}

// ======================= KNN: 1024 blocks, 8 q/block x 32 thr/q, tree merge =======================
__global__ __launch_bounds__(256) void knn_kernel(
    const float* __restrict__ xyz_q, const float* __restrict__ axyz, int* __restrict__ knn)
{
    __shared__ float sax[NA], say[NA], saz[NA];
    __shared__ double cd[8*257];
    __shared__ int    ci[8*257];
    const int t = threadIdx.x;
    const int b  = blockIdx.x >> 9;
    const int qi = t >> 5;
    const int q  = ((blockIdx.x & 511) << 3) + qi;
    const int g  = t & 31;
    for (int i=t;i<NA;i+=256) {
        const float* ap = axyz + (size_t)(b*NA+i)*3;
        sax[i]=ap[0]; say[i]=ap[1]; saz[i]=ap[2];
    }
    __syncthreads();
    const double qx = (double)xyz_q[(size_t)(b*NQ+q)*3+0];
    const double qy = (double)xyz_q[(size_t)(b*NQ+q)*3+1];
    const double qz = (double)xyz_q[(size_t)(b*NQ+q)*3+2];
    const double qq = (qx*qx + qy*qy) + qz*qz;
    double best[8]; int bid[8];
    #pragma unroll
    for (int j=0;j<8;j++){ best[j]=1.0e300; bid[j]=0; }
    for (int jj=0; jj<64; jj++) {
        const int i = jj*32 + g;
        double ax=(double)sax[i], ay=(double)say[i], az=(double)saz[i];
        double aa  = (ax*ax + ay*ay) + az*az;
        double dot = (qx*ax + qy*ay) + qz*az;
        double dd  = (qq + aa) - 2.0*dot;
        if (dd < best[7]) {
            best[7]=dd; bid[7]=i;
            #pragma unroll
            for (int j=7;j>0;--j) if (best[j] < best[j-1]) {
                double tf=best[j]; best[j]=best[j-1]; best[j-1]=tf;
                int ti=bid[j]; bid[j]=bid[j-1]; bid[j-1]=ti;
            }
        }
    }
    const int base = qi*257;
    #pragma unroll
    for (int j=0;j<8;j++){ cd[base+g*8+j]=best[j]; ci[base+g*8+j]=bid[j]; }
    for (int s=16; s>=1; s>>=1) {
        __syncthreads();
        if (g < s) {
            double la[8], lb[8]; int ia[8], ib[8];
            #pragma unroll
            for (int j=0;j<8;j++){ la[j]=cd[base+g*8+j]; ia[j]=ci[base+g*8+j];
                                   lb[j]=cd[base+(g+s)*8+j]; ib[j]=ci[base+(g+s)*8+j]; }
            double lo[8]; int io[8];
            int pa=0, pb=0;
            #pragma unroll
            for (int m=0;m<8;m++) {
                bool ta = (pb>=8) || (pa<8 && la[pa] <= lb[pb]);
                if (ta) { lo[m]=la[pa]; io[m]=ia[pa]; pa++; }
                else    { lo[m]=lb[pb]; io[m]=ib[pb]; pb++; }
            }
            #pragma unroll
            for (int j=0;j<8;j++){ cd[base+g*8+j]=lo[j]; ci[base+g*8+j]=io[j]; }
        }
    }
    __syncthreads();
    if (g < 8) knn[(size_t)(b*NQ+q)*8+g] = ci[base+g];
}

// ======================= weight prep =======================
// hi/lo (decoder)
__global__ __launch_bounds__(256) void prep_w(
    const float* __restrict__ W, short* __restrict__ Wh, short* __restrict__ Wl)
{
    const int gid = blockIdx.x*256 + threadIdx.x;
    const int n  = gid & 511;
    const int kc = (gid >> 9) * 8;
    short hi[8], lo[8];
    #pragma unroll
    for (int j=0;j<8;j++) split2(W[(size_t)(kc+j)*512 + n], hi[j], lo[j]);
    *(short4*)&Wh[(size_t)n*512 + kc]     = make_short4(hi[0],hi[1],hi[2],hi[3]);
    *(short4*)&Wh[(size_t)n*512 + kc + 4] = make_short4(hi[4],hi[5],hi[6],hi[7]);
    *(short4*)&Wl[(size_t)n*512 + kc]     = make_short4(lo[0],lo[1],lo[2],lo[3]);
    *(short4*)&Wl[(size_t)n*512 + kc + 4] = make_short4(lo[4],lo[5],lo[6],lo[7]);
}
// single bf16 (attention)
__global__ __launch_bounds__(256) void prep_w1(
    const float* __restrict__ W, short* __restrict__ Wb)
{
    const int gid = blockIdx.x*256 + threadIdx.x;
    const int n  = gid & 511;
    const int kc = (gid >> 9) * 8;
    short o[8];
    #pragma unroll
    for (int j=0;j<8;j++) o[j] = (short)f2b(W[(size_t)(kc+j)*512 + n]);
    *(short4*)&Wb[(size_t)n*512 + kc]     = make_short4(o[0],o[1],o[2],o[3]);
    *(short4*)&Wb[(size_t)n*512 + kc + 4] = make_short4(o[4],o[5],o[6],o[7]);
}

// ======================= fp32 -> single bf16 =======================
__global__ __launch_bounds__(256) void cvt_bf16(
    const float* __restrict__ X, short* __restrict__ Xb)
{
    const size_t i0 = ((size_t)blockIdx.x*256 + threadIdx.x)*8;
    float4 a = *(const float4*)(X+i0), bq = *(const float4*)(X+i0+4);
    float v[8] = {a.x,a.y,a.z,a.w,bq.x,bq.y,bq.z,bq.w};
    short o[8];
    #pragma unroll
    for (int j=0;j<8;j++) o[j] = (short)f2b(v[j]);
    *(short4*)(Xb+i0)   = make_short4(o[0],o[1],o[2],o[3]);
    *(short4*)(Xb+i0+4) = make_short4(o[4],o[5],o[6],o[7]);
}

// ======== x1 GEMM: 128 thr, 2 waves of 64x32, A/B single bf16 ========
// OUT_MODE: 0=fp32, 3=bf16
template<int OUT_MODE, int RELU_OUT>
__global__ __launch_bounds__(128) void gemm1(
    const short* __restrict__ Ab, const short* __restrict__ Wb,
    const float* __restrict__ bias,
    float* __restrict__ Cf, short* __restrict__ Cb)
{
    __shared__ short As[64*LDK], Bs[64*LDK];
    const int t = threadIdx.x;
    const int row0 = blockIdx.y*64, col0 = blockIdx.x*64;
    const int lane = t & 63, w = t >> 6;
    const int n0 = w*32;
    const int fl = lane & 15, quad = lane >> 4;
    const int s_row = t >> 1, s_k = (t & 1) * 16;

    f32x4 zero = {0.f,0.f,0.f,0.f};
    f32x4 acc[4][2];
    #pragma unroll
    for (int i=0;i<4;i++){ acc[i][0]=zero; acc[i][1]=zero; }

    for (int k0 = 0; k0 < 512; k0 += 32) {
        const size_t a_off = (size_t)(row0+s_row)*512 + k0 + s_k;
        *(int4*)&As[s_row*LDK + s_k]     = *(const int4*)(Ab + a_off);
        *(int4*)&As[s_row*LDK + s_k + 8] = *(const int4*)(Ab + a_off + 8);
        const size_t b_off = (size_t)(col0+s_row)*512 + k0 + s_k;
        *(int4*)&Bs[s_row*LDK + s_k]     = *(const int4*)(Wb + b_off);
        *(int4*)&Bs[s_row*LDK + s_k + 8] = *(const int4*)(Wb + b_off + 8);
        __syncthreads();
        bf16x8 fa[4], fb[2];
        #pragma unroll
        for (int i=0;i<4;i++) fa[i] = *(const bf16x8*)&As[(i*16 + fl)*LDK + quad*8];
        #pragma unroll
        for (int j=0;j<2;j++) fb[j] = *(const bf16x8*)&Bs[(n0 + j*16 + fl)*LDK + quad*8];
        #pragma unroll
        for (int i=0;i<4;i++)
        #pragma unroll
        for (int j=0;j<2;j++)
            acc[i][j] = __builtin_amdgcn_mfma_f32_16x16x32_bf16(fa[i], fb[j], acc[i][j], 0,0,0);
        __syncthreads();
    }
    #pragma unroll
    for (int i=0;i<4;i++)
    #pragma unroll
    for (int j=0;j<2;j++) {
        const int col = col0 + n0 + j*16 + fl;
        const float bb = bias ? bias[col] : 0.f;
        #pragma unroll
        for (int r=0;r<4;r++) {
            const int row = row0 + i*16 + quad*4 + r;
            const size_t off = (size_t)row*512 + col;
            float v = acc[i][j][r] + bb;
            if (RELU_OUT) v = fmaxf(v,0.f);
            if (OUT_MODE == 0) Cf[off] = v;
            else               Cb[off] = (short)f2b(v);
        }
    }
}

// ======== fused pos GEMM (x1): A = relu(d@d1w+d1b) generated in staging ========
__global__ __launch_bounds__(128) void gemm_pos(
    const float* __restrict__ xyz_q, const float* __restrict__ axyz, const int* __restrict__ knn,
    const float* __restrict__ d1w, const float* __restrict__ d1b,
    const short* __restrict__ Wb, const float* __restrict__ bias,
    short* __restrict__ Cb, int qbase)
{
    __shared__ short As[64*LDK], Bs[64*LDK];
    __shared__ float sdx[64], sdy[64], sdz[64];
    const int t = threadIdx.x;
    const int row0 = blockIdx.y*64, col0 = blockIdx.x*64;
    const int lane = t & 63, w = t >> 6;
    const int n0 = w*32;
    const int fl = lane & 15, quad = lane >> 4;
    const int s_row = t >> 1, s_k = (t & 1) * 16;
    if (t < 64) {
        int gr = qbase*8 + row0 + t;
        int b  = gr >> 15;
        int gq = gr >> 3;
        int idx = knn[gr];
        const float* qp = xyz_q + (size_t)gq*3;
        const float* ap = axyz + (size_t)(b*NA + idx)*3;
        sdx[t]=qp[0]-ap[0]; sdy[t]=qp[1]-ap[1]; sdz[t]=qp[2]-ap[2];
    }
    __syncthreads();
    const float dx = sdx[s_row], dy = sdy[s_row], dz = sdz[s_row];

    f32x4 zero = {0.f,0.f,0.f,0.f};
    f32x4 acc[4][2];
    #pragma unroll
    for (int i=0;i<4;i++){ acc[i][0]=zero; acc[i][1]=zero; }

    for (int k0 = 0; k0 < 512; k0 += 32) {
        {
            const int k = k0 + s_k;
            short o[16];
            #pragma unroll
            for (int u=0;u<16;u+=4) {
                float4 w0 = ld4(d1w + k + u);
                float4 w1 = ld4(d1w + 512 + k + u);
                float4 w2 = ld4(d1w + 1024 + k + u);
                float4 bb = ld4(d1b + k + u);
                o[u+0] = (short)f2b(fmaxf(fmaf(dx,w0.x,fmaf(dy,w1.x,fmaf(dz,w2.x,bb.x))),0.f));
                o[u+1] = (short)f2b(fmaxf(fmaf(dx,w0.y,fmaf(dy,w1.y,fmaf(dz,w2.y,bb.y))),0.f));
                o[u+2] = (short)f2b(fmaxf(fmaf(dx,w0.z,fmaf(dy,w1.z,fmaf(dz,w2.z,bb.z))),0.f));
                o[u+3] = (short)f2b(fmaxf(fmaf(dx,w0.w,fmaf(dy,w1.w,fmaf(dz,w2.w,bb.w))),0.f));
            }
            #pragma unroll
            for (int u=0;u<16;u+=4)
                *(short4*)&As[s_row*LDK + s_k + u] = make_short4(o[u],o[u+1],o[u+2],o[u+3]);
        }
        const size_t b_off = (size_t)(col0+s_row)*512 + k0 + s_k;
        *(int4*)&Bs[s_row*LDK + s_k]     = *(const int4*)(Wb + b_off);
        *(int4*)&Bs[s_row*LDK + s_k + 8] = *(const int4*)(Wb + b_off + 8);
        __syncthreads();
        bf16x8 fa[4], fb[2];
        #pragma unroll
        for (int i=0;i<4;i++) fa[i] = *(const bf16x8*)&As[(i*16 + fl)*LDK + quad*8];
        #pragma unroll
        for (int j=0;j<2;j++) fb[j] = *(const bf16x8*)&Bs[(n0 + j*16 + fl)*LDK + quad*8];
        #pragma unroll
        for (int i=0;i<4;i++)
        #pragma unroll
        for (int j=0;j<2;j++)
            acc[i][j] = __builtin_amdgcn_mfma_f32_16x16x32_bf16(fa[i], fb[j], acc[i][j], 0,0,0);
        __syncthreads();
    }
    #pragma unroll
    for (int i=0;i<4;i++)
    #pragma unroll
    for (int j=0;j<2;j++) {
        const int col = col0 + n0 + j*16 + fl;
        const float bb = bias[col];
        #pragma unroll
        for (int r=0;r<4;r++) {
            const int row = row0 + i*16 + quad*4 + r;
            Cb[(size_t)row*512 + col] = (short)f2b(acc[i][j][r] + bb);
        }
    }
}

// ======== fused g1 GEMM (x1): A = q_attn - k + pos assembled in staging ========
__global__ __launch_bounds__(128) void gemm_g1(
    const float* __restrict__ q_attn, const float* __restrict__ kgv,
    const short* __restrict__ ak_bf, const short* __restrict__ pos_bf, const int* __restrict__ knn,
    const short* __restrict__ Wb, const float* __restrict__ bias,
    short* __restrict__ Cb, int qbase)
{
    __shared__ short As[64*LDK], Bs[64*LDK];
    __shared__ int s_aoff[64], s_poff[64];
    const int t = threadIdx.x;
    const int row0 = blockIdx.y*64, col0 = blockIdx.x*64;
    const int lane = t & 63, w = t >> 6;
    const int n0 = w*32;
    const int fl = lane & 15, quad = lane >> 4;
    const int s_row = t >> 1, s_k = (t & 1) * 16;
    const int b = qbase >> 12;
    if (t < 64) {
        int g = row0 + t;
        int q = g / 9, n = g - q*9;
        if (n < 8) { s_aoff[t] = b*NA + knn[(size_t)(qbase + q)*8 + n]; s_poff[t] = q*8 + n; }
        else       { s_aoff[t] = -1; s_poff[t] = 0; }
    }
    __syncthreads();
    const int ao = s_aoff[s_row];
    const int po = s_poff[s_row];

    f32x4 zero = {0.f,0.f,0.f,0.f};
    f32x4 acc[4][2];
    #pragma unroll
    for (int i=0;i<4;i++){ acc[i][0]=zero; acc[i][1]=zero; }

    for (int k0 = 0; k0 < 512; k0 += 32) {
        {
            const int k = k0 + s_k;
            short o[16];
            if (ao >= 0) {
                #pragma unroll
                for (int u=0;u<16;u+=4) {
                    float4 qa = ld4(q_attn + b*512 + k + u);
                    ushort4 kv = *(const ushort4*)(ak_bf + (size_t)ao*512 + k + u);
                    ushort4 pv = *(const ushort4*)(pos_bf + (size_t)po*512 + k + u);
                    o[u+0] = (short)f2b(qa.x - b2f(kv.x) + b2f(pv.x));
                    o[u+1] = (short)f2b(qa.y - b2f(kv.y) + b2f(pv.y));
                    o[u+2] = (short)f2b(qa.z - b2f(kv.z) + b2f(pv.z));
                    o[u+3] = (short)f2b(qa.w - b2f(kv.w) + b2f(pv.w));
                }
            } else {
                #pragma unroll
                for (int u=0;u<16;u+=4) {
                    float4 qa = ld4(q_attn + b*512 + k + u);
                    float4 gk = ld4(kgv + b*512 + k + u);
                    o[u+0] = (short)f2b(qa.x - gk.x);
                    o[u+1] = (short)f2b(qa.y - gk.y);
                    o[u+2] = (short)f2b(qa.z - gk.z);
                    o[u+3] = (short)f2b(qa.w - gk.w);
                }
            }
            #pragma unroll
            for (int u=0;u<16;u+=4)
                *(short4*)&As[s_row*LDK + s_k + u] = make_short4(o[u],o[u+1],o[u+2],o[u+3]);
        }
        const size_t b_off = (size_t)(col0+s_row)*512 + k0 + s_k;
        *(int4*)&Bs[s_row*LDK + s_k]     = *(const int4*)(Wb + b_off);
        *(int4*)&Bs[s_row*LDK + s_k + 8] = *(const int4*)(Wb + b_off + 8);
        __syncthreads();
        bf16x8 fa[4], fb[2];
        #pragma unroll
        for (int i=0;i<4;i++) fa[i] = *(const bf16x8*)&As[(i*16 + fl)*LDK + quad*8];
        #pragma unroll
        for (int j=0;j<2;j++) fb[j] = *(const bf16x8*)&Bs[(n0 + j*16 + fl)*LDK + quad*8];
        #pragma unroll
        for (int i=0;i<4;i++)
        #pragma unroll
        for (int j=0;j<2;j++)
            acc[i][j] = __builtin_amdgcn_mfma_f32_16x16x32_bf16(fa[i], fb[j], acc[i][j], 0,0,0);
        __syncthreads();
    }
    #pragma unroll
    for (int i=0;i<4;i++)
    #pragma unroll
    for (int j=0;j<2;j++) {
        const int col = col0 + n0 + j*16 + fl;
        const float bb = bias[col];
        #pragma unroll
        for (int r=0;r<4;r++) {
            const int row = row0 + i*16 + quad*4 + r;
            Cb[(size_t)row*512 + col] = (short)f2b(fmaxf(acc[i][j][r] + bb, 0.f));
        }
    }
}

// ======== x3 decoder GEMM: 128 thr, 2 waves of 64x32, A h/l + B h/l ========
// OUT_MODE: 0=fp32; 1=split bf16; 2=fp32 + split(relu(v))
template<int OUT_MODE, int RELU_OUT, int HAS_ADD>
__global__ __launch_bounds__(128) void gemm3(
    const short* __restrict__ Ah, const short* __restrict__ Al,
    const short* __restrict__ Wh, const short* __restrict__ Wl,
    const float* __restrict__ bias, const float* __restrict__ addend,
    float* __restrict__ Cf, short* __restrict__ Ch, short* __restrict__ Cl)
{
    __shared__ short As_h[64*LDK], As_l[64*LDK], Bs_h[64*LDK], Bs_l[64*LDK];
    const int t = threadIdx.x;
    const int row0 = blockIdx.y*64, col0 = blockIdx.x*64;
    const int lane = t & 63, w = t >> 6;
    const int n0 = w*32;
    const int fl = lane & 15, quad = lane >> 4;
    const int s_row = t >> 1, s_k = (t & 1) * 16;

    f32x4 zero = {0.f,0.f,0.f,0.f};
    f32x4 acc[4][2];
    #pragma unroll
    for (int i=0;i<4;i++){ acc[i][0]=zero; acc[i][1]=zero; }

    for (int k0 = 0; k0 < 512; k0 += 32) {
        const size_t a_off = (size_t)(row0+s_row)*512 + k0 + s_k;
        *(int4*)&As_h[s_row*LDK + s_k]     = *(const int4*)(Ah + a_off);
        *(int4*)&As_h[s_row*LDK + s_k + 8] = *(const int4*)(Ah + a_off + 8);
        *(int4*)&As_l[s_row*LDK + s_k]     = *(const int4*)(Al + a_off);
        *(int4*)&As_l[s_row*LDK + s_k + 8] = *(const int4*)(Al + a_off + 8);
        const size_t b_off = (size_t)(col0+s_row)*512 + k0 + s_k;
        *(int4*)&Bs_h[s_row*LDK + s_k]     = *(const int4*)(Wh + b_off);
        *(int4*)&Bs_h[s_row*LDK + s_k + 8] = *(const int4*)(Wh + b_off + 8);
        *(int4*)&Bs_l[s_row*LDK + s_k]     = *(const int4*)(Wl + b_off);
        *(int4*)&Bs_l[s_row*LDK + s_k + 8] = *(const int4*)(Wl + b_off + 8);
        __syncthreads();
        bf16x8 fah[4], fal[4], fbh[2], fbl[2];
        #pragma unroll
        for (int i=0;i<4;i++) {
            fah[i] = *(const bf16x8*)&As_h[(i*16 + fl)*LDK + quad*8];
            fal[i] = *(const bf16x8*)&As_l[(i*16 + fl)*LDK + quad*8];
        }
        #pragma unroll
        for (int j=0;j<2;j++) {
            fbh[j] = *(const bf16x8*)&Bs_h[(n0 + j*16 + fl)*LDK + quad*8];
            fbl[j] = *(const bf16x8*)&Bs_l[(n0 + j*16 + fl)*LDK + quad*8];
        }
        #pragma unroll
        for (int i=0;i<4;i++)
        #pragma unroll
        for (int j=0;j<2;j++)
            acc[i][j] = __builtin_amdgcn_mfma_f32_16x16x32_bf16(fah[i], fbh[j], acc[i][j], 0,0,0);
        #pragma unroll
        for (int i=0;i<4;i++)
        #pragma unroll
        for (int j=0;j<2;j++)
            acc[i][j] = __builtin_amdgcn_mfma_f32_16x16x32_bf16(fah[i], fbl[j], acc[i][j], 0,0,0);
        #pragma unroll
        for (int i=0;i<4;i++)
        #pragma unroll
        for (int j=0;j<2;j++)
            acc[i][j] = __builtin_amdgcn_mfma_f32_16x16x32_bf16(fal[i], fbh[j], acc[i][j], 0,0,0);
        __syncthreads();
    }
    #pragma unroll
    for (int i=0;i<4;i++)
    #pragma unroll
    for (int j=0;j<2;j++) {
        const int col = col0 + n0 + j*16 + fl;
        const float bb = bias ? bias[col] : 0.f;
        #pragma unroll
        for (int r=0;r<4;r++) {
            const int row = row0 + i*16 + quad*4 + r;
            const size_t off = (size_t)row*512 + col;
            float v = acc[i][j][r] + bb;
            if (HAS_ADD) v += addend[off];
            if (OUT_MODE == 0) {
                if (RELU_OUT) v = fmaxf(v,0.f);
                Cf[off] = v;
            } else if (OUT_MODE == 1) {
                if (RELU_OUT) v = fmaxf(v,0.f);
                short h,l; split2(v,h,l); Ch[off]=h; Cl[off]=l;
            } else {
                Cf[off] = v;
                short h,l; split2(fmaxf(v,0.f),h,l); Ch[off]=h; Cl[off]=l;
            }
        }
    }
}

// ======================= softmax + aggregation =======================
__global__ __launch_bounds__(256) void softmax_agg(
    const short* __restrict__ attn_preb, const short* __restrict__ pos_bf,
    const short* __restrict__ av_bf, const float* __restrict__ vgv,
    const int* __restrict__ knn, short* __restrict__ lath, short* __restrict__ latl, int qbase)
{
    __shared__ int sk[8];
    const int q = blockIdx.x;
    const int gq = qbase + q;
    const int b = qbase >> 12;
    const int t = threadIdx.x;
    if (t < 8) sk[t] = knn[(size_t)gq*8 + t];
    __syncthreads();
    for (int c = t; c < 512; c += 256) {
        float p[9];
        #pragma unroll
        for (int n=0;n<9;n++) p[n] = b2f((unsigned short)attn_preb[(size_t)(q*9+n)*512 + c]);
        float m = p[0];
        #pragma unroll
        for (int n=1;n<9;n++) m = fmaxf(m, p[n]);
        float e[9], s = 0.f;
        #pragma unroll
        for (int n=0;n<9;n++){ e[n] = expf(p[n]-m); s += e[n]; }
        const float inv = 1.0f / s;
        float acc = 0.f;
        #pragma unroll
        for (int n=0;n<8;n++) {
            float vv = b2f((unsigned short)av_bf[(size_t)(b*NA + sk[n])*512 + c])
                     + b2f((unsigned short)pos_bf[(size_t)(q*8+n)*512 + c]);
            acc = fmaf(e[n]*inv, vv, acc);
        }
        acc = fmaf(e[8]*inv, vgv[b*512 + c], acc);
        short h,l; split2(acc,h,l);
        lath[(size_t)gq*512 + c] = h; latl[(size_t)gq*512 + c] = l;
    }
}

// ======================= PE + first decoder layer =======================
__global__ __launch_bounds__(256) void pe_fc(
    const float* __restrict__ xyz_q, const float* __restrict__ fw, const float* __restrict__ fb,
    float* __restrict__ net)
{
    __shared__ float spe[16*60];
    const int t = threadIdx.x;
    const int q0 = blockIdx.x * 16;
    for (int i=t;i<960;i+=256) {
        int ql = i/60, j = i - ql*60;
        int l = j/6; int r6 = j - l*6; int s = r6/3; int d = r6 - s*3;
        float pv = xyz_q[(size_t)(q0+ql)*3 + d];
        float a = pv * (3.14159265358979323846f * (float)(1<<l));
        spe[ql*60+j] = (s==0) ? sinf(a) : cosf(a);
    }
    __syncthreads();
    float acc0[16], acc1[16];
    #pragma unroll
    for (int ql=0;ql<16;ql++){ acc0[ql]=0.f; acc1[ql]=0.f; }
    const int c0 = t, c1 = t + 256;
    for (int k=0;k<60;k++) {
        float w0 = fw[k*512 + c0];
        float w1 = fw[k*512 + c1];
        #pragma unroll
        for (int ql=0;ql<16;ql++) {
            float pv = spe[ql*60+k];
            acc0[ql] = fmaf(pv, w0, acc0[ql]);
            acc1[ql] = fmaf(pv, w1, acc1[ql]);
        }
    }
    const float b0v = fb[c0], b1v = fb[c1];
    #pragma unroll
    for (int ql=0;ql<16;ql++) {
        net[(size_t)(q0+ql)*512 + c0] = acc0[ql] + b0v;
        net[(size_t)(q0+ql)*512 + c1] = acc1[ql] + b1v;
    }
}

// ======================= launch =======================
extern "C" void kernel_launch(void* const* d_in, const int* in_sizes, int n_in,
                              void* d_out, int out_size, void* d_ws, size_t ws_size,
                              hipStream_t stream) {
    const float* xyz_q  = (const float*)d_in[0];
    const float* gf     = (const float*)d_in[1];
    const float* axyz   = (const float*)d_in[2];
    const float* afeat  = (const float*)d_in[3];
    const float* w_qs   = (const float*)d_in[4];
    const float* w_ks   = (const float*)d_in[5];
    const float* w_vs   = (const float*)d_in[6];
    const float* w_kg   = (const float*)d_in[7];
    const float* w_vg   = (const float*)d_in[8];
    const float* d1_w   = (const float*)d_in[9];
    const float* d1_b   = (const float*)d_in[10];
    const float* d2_w   = (const float*)d_in[11];
    const float* d2_b   = (const float*)d_in[12];
    const float* g1_w   = (const float*)d_in[13];
    const float* g1_b   = (const float*)d_in[14];
    const float* g2_w   = (const float*)d_in[15];
    const float* g2_b   = (const float*)d_in[16];
    const float* fc_p_w = (const float*)d_in[17];
    const float* fc_p_b = (const float*)d_in[18];
    const float* fc_c_w = (const float*)d_in[19];
    const float* fc_c_b = (const float*)d_in[20];
    const float* blk0_w = (const float*)d_in[21];
    const float* blk0_b = (const float*)d_in[22];
    const float* blk1_w = (const float*)d_in[23];
    const float* blk1_b = (const float*)d_in[24];
    float* out = (float*)d_out;

    const size_t MB = 1u<<20;
    char* base = (char*)d_ws;
    // ---- persistent (21 MB) ----
    float* q_attn = (float*)base;
    float* kgv    = q_attn + 1024;
    float* vgv    = kgv + 1024;
    int*   knn    = (int*)(base + 16*1024);
    short* wksb = (short*)(base + 1*MB);      // 0.5 MB each
    short* wvsb = wksb + 262144;
    short* wd2b = wvsb + 262144;
    short* wg1b = wd2b + 262144;
    short* wg2b = wg1b + 262144;              // ends 3.5 MB
    short* wth  = (short*)(base + 3*MB + 524288);   // 0.5 MB
    short* wtl  = wth + 262144;                      // ends 4.5 MB
    short* lath = (short*)(base + 5*MB);
    short* latl = (short*)(base + 13*MB);
    // ---- transient T (34 MB): total 55 MB ----
    char* T = base + 21*MB;
    short* ak_bf = (short*)T;                    // 4 MB
    short* av_bf = (short*)(T + 4*MB);           // 4 MB
    short* posb  = (short*)(T + 8*MB);           // 8 MB
    short* yb    = (short*)(T + 16*MB);          // 9 MB
    short* attn_preb = (short*)(T + 25*MB);      // 9 MB
    short* af_bf = (short*)(T + 8*MB);           // 4 MB (phase A overlay)
    short* nrh = (short*)T;            short* nrl = (short*)(T + 8*MB);
    short* hdh = (short*)(T + 16*MB);  short* hdl = (short*)(T + 24*MB);
    if ((size_t)(55*MB) > ws_size) return;

    proj_small<<<dim3(6), dim3(256), 0, stream>>>(gf, w_qs, w_kg, w_vg, q_attn, kgv, vgv);
    knn_kernel<<<dim3(1024), dim3(256), 0, stream>>>(xyz_q, axyz, knn);

    cvt_bf16<<<dim3(1024), dim3(256), 0, stream>>>(afeat, af_bf);
    prep_w1<<<dim3(128), dim3(256), 0, stream>>>(w_ks, wksb);
    prep_w1<<<dim3(128), dim3(256), 0, stream>>>(w_vs, wvsb);
    gemm1<3,0><<<dim3(8,64), dim3(128), 0, stream>>>(af_bf, wksb, nullptr, nullptr, ak_bf);
    gemm1<3,0><<<dim3(8,64), dim3(128), 0, stream>>>(af_bf, wvsb, nullptr, nullptr, av_bf);

    prep_w1<<<dim3(128), dim3(256), 0, stream>>>(d2_w, wd2b);
    prep_w1<<<dim3(128), dim3(256), 0, stream>>>(g1_w, wg1b);
    prep_w1<<<dim3(128), dim3(256), 0, stream>>>(g2_w, wg2b);

    for (int qbase = 0; qbase < B*NQ; qbase += CH) {
        gemm_pos<<<dim3(8, CH*8/64), dim3(128), 0, stream>>>(xyz_q, axyz, knn, d1_w, d1_b, wd2b, d2_b, posb, qbase);
        gemm_g1<<<dim3(8, CH*9/64), dim3(128), 0, stream>>>(q_attn, kgv, ak_bf, posb, knn, wg1b, g1_b, yb, qbase);
        gemm1<3,0><<<dim3(8, CH*9/64), dim3(128), 0, stream>>>(yb, wg2b, g2_b, nullptr, attn_preb);
        softmax_agg<<<dim3(CH), dim3(256), 0, stream>>>(attn_preb, posb, av_bf, vgv, knn, lath, latl, qbase);
    }

    pe_fc<<<dim3(512), dim3(256), 0, stream>>>(xyz_q, fc_p_w, fc_p_b, out);
    for (int i=0;i<5;i++) {
        const float* cw  = fc_c_w + (size_t)i*512*512;
        const float* cb  = fc_c_b + (size_t)i*512;
        const float* b0w = blk0_w + (size_t)i*512*512;
        const float* b0b = blk0_b + (size_t)i*512;
        const float* b1w = blk1_w + (size_t)i*512*512;
        const float* b1b = blk1_b + (size_t)i*512;
        prep_w<<<dim3(128), dim3(256), 0, stream>>>(cw, wth, wtl);
        gemm3<2,0,1><<<dim3(8,128), dim3(128), 0, stream>>>(lath, latl, wth, wtl, cb, out, out, nrh, nrl);
        prep_w<<<dim3(128), dim3(256), 0, stream>>>(b0w, wth, wtl);
        gemm3<1,1,0><<<dim3(8,128), dim3(128), 0, stream>>>(nrh, nrl, wth, wtl, b0b, nullptr, nullptr, hdh, hdl);
        prep_w<<<dim3(128), dim3(256), 0, stream>>>(b1w, wth, wtl);
        gemm3<0,0,1><<<dim3(8,128), dim3(128), 0, stream>>>(hdh, hdl, wth, wtl, b1b, out, out, nullptr, nullptr);
    }
}

// Round 12
// 1313.637 us; speedup vs baseline: 1.1880x; 1.1880x over previous
//
#include <hip/hip_runtime.h>

#define B 2
#define NQ 4096
#define NA 2048
#define CH 1024  // attention chunk (8 chunks)
#define LDK 40   // LDS row stride (shorts)

typedef __attribute__((ext_vector_type(8))) short bf16x8;
typedef __attribute__((ext_vector_type(4))) float f32x4;

__device__ __forceinline__ float b2f(unsigned short u){ union{unsigned i; float f;} c; c.i=((unsigned)u)<<16; return c.f; }
__device__ __forceinline__ unsigned short f2b(float f){ union{float f; unsigned u;} c; c.f=f; unsigned u=c.u; u += 0x7FFFu + ((u>>16)&1u); return (unsigned short)(u>>16); }
__device__ __forceinline__ void split2(float x, short& h, short& l){
    unsigned short hh = f2b(x); h = (short)hh; l = (short)f2b(x - b2f(hh));
}
__device__ __forceinline__ float4 ld4(const float* p){ return *(const float4*)p; }

// ======================= small projections =======================
__global__ __launch_bounds__(256) void proj_small(
    const float* __restrict__ gf,
    const float* __restrict__ w_qs, const float* __restrict__ w_kg, const float* __restrict__ w_vg,
    float* __restrict__ q_attn, float* __restrict__ kgv, float* __restrict__ vgv)
{
    int mat = blockIdx.x >> 1, b = blockIdx.x & 1;
    const float* W = (mat==0) ? w_qs : (mat==1 ? w_kg : w_vg);
    float* O       = (mat==0) ? q_attn : (mat==1 ? kgv : vgv);
    __shared__ float sg[512];
    int t = threadIdx.x;
    for (int i=t;i<512;i+=256) sg[i] = gf[b*512+i];
    __syncthreads();
    for (int c=t;c<512;c+=256) {
        float acc = 0.f;
        for (int k=0;k<512;k++) acc = fmaf(sg[k], W[k*512+c], acc);
        O[b*512+c] = acc;
    }
}

// ======================= KNN: 1024 blocks, 8 q/block x 32 thr/q, tree merge =======================
__global__ __launch_bounds__(256) void knn_kernel(
    const float* __restrict__ xyz_q, const float* __restrict__ axyz, int* __restrict__ knn)
{
    __shared__ float sax[NA], say[NA], saz[NA];
    __shared__ double cd[8*257];
    __shared__ int    ci[8*257];
    const int t = threadIdx.x;
    const int b  = blockIdx.x >> 9;
    const int qi = t >> 5;
    const int q  = ((blockIdx.x & 511) << 3) + qi;
    const int g  = t & 31;
    for (int i=t;i<NA;i+=256) {
        const float* ap = axyz + (size_t)(b*NA+i)*3;
        sax[i]=ap[0]; say[i]=ap[1]; saz[i]=ap[2];
    }
    __syncthreads();
    const double qx = (double)xyz_q[(size_t)(b*NQ+q)*3+0];
    const double qy = (double)xyz_q[(size_t)(b*NQ+q)*3+1];
    const double qz = (double)xyz_q[(size_t)(b*NQ+q)*3+2];
    const double qq = (qx*qx + qy*qy) + qz*qz;
    double best[8]; int bid[8];
    #pragma unroll
    for (int j=0;j<8;j++){ best[j]=1.0e300; bid[j]=0; }
    for (int jj=0; jj<64; jj++) {
        const int i = jj*32 + g;
        double ax=(double)sax[i], ay=(double)say[i], az=(double)saz[i];
        double aa  = (ax*ax + ay*ay) + az*az;
        double dot = (qx*ax + qy*ay) + qz*az;
        double dd  = (qq + aa) - 2.0*dot;
        if (dd < best[7]) {
            best[7]=dd; bid[7]=i;
            #pragma unroll
            for (int j=7;j>0;--j) if (best[j] < best[j-1]) {
                double tf=best[j]; best[j]=best[j-1]; best[j-1]=tf;
                int ti=bid[j]; bid[j]=bid[j-1]; bid[j-1]=ti;
            }
        }
    }
    const int base = qi*257;
    #pragma unroll
    for (int j=0;j<8;j++){ cd[base+g*8+j]=best[j]; ci[base+g*8+j]=bid[j]; }
    for (int s=16; s>=1; s>>=1) {
        __syncthreads();
        if (g < s) {
            double la[8], lb[8]; int ia[8], ib[8];
            #pragma unroll
            for (int j=0;j<8;j++){ la[j]=cd[base+g*8+j]; ia[j]=ci[base+g*8+j];
                                   lb[j]=cd[base+(g+s)*8+j]; ib[j]=ci[base+(g+s)*8+j]; }
            double lo[8]; int io[8];
            int pa=0, pb=0;
            #pragma unroll
            for (int m=0;m<8;m++) {
                bool ta = (pb>=8) || (pa<8 && la[pa] <= lb[pb]);
                if (ta) { lo[m]=la[pa]; io[m]=ia[pa]; pa++; }
                else    { lo[m]=lb[pb]; io[m]=ib[pb]; pb++; }
            }
            #pragma unroll
            for (int j=0;j<8;j++){ cd[base+g*8+j]=lo[j]; ci[base+g*8+j]=io[j]; }
        }
    }
    __syncthreads();
    if (g < 8) knn[(size_t)(b*NQ+q)*8+g] = ci[base+g];
}

// ======================= weight prep =======================
// 5 attention matrices -> single bf16 [n][k], one launch
__global__ __launch_bounds__(256) void prep_w5(
    const float* __restrict__ W0, const float* __restrict__ W1, const float* __restrict__ W2,
    const float* __restrict__ W3, const float* __restrict__ W4,
    short* __restrict__ O0, short* __restrict__ O1, short* __restrict__ O2,
    short* __restrict__ O3, short* __restrict__ O4)
{
    const int m = blockIdx.x >> 7;
    const float* W = (m==0)?W0:(m==1)?W1:(m==2)?W2:(m==3)?W3:W4;
    short* Wb      = (m==0)?O0:(m==1)?O1:(m==2)?O2:(m==3)?O3:O4;
    const int gid = (blockIdx.x & 127)*256 + threadIdx.x;
    const int n  = gid & 511;
    const int kc = (gid >> 9) * 8;
    short o[8];
    #pragma unroll
    for (int j=0;j<8;j++) o[j] = (short)f2b(W[(size_t)(kc+j)*512 + n]);
    *(short4*)&Wb[(size_t)n*512 + kc]     = make_short4(o[0],o[1],o[2],o[3]);
    *(short4*)&Wb[(size_t)n*512 + kc + 4] = make_short4(o[4],o[5],o[6],o[7]);
}
// 3 decoder matrices -> hi/lo [n][k], one launch per decoder layer
__global__ __launch_bounds__(256) void prep_w3(
    const float* __restrict__ W0, const float* __restrict__ W1, const float* __restrict__ W2,
    short* __restrict__ H0, short* __restrict__ L0,
    short* __restrict__ H1, short* __restrict__ L1,
    short* __restrict__ H2, short* __restrict__ L2)
{
    const int m = blockIdx.x >> 7;
    const float* W = (m==0)?W0:(m==1)?W1:W2;
    short* Wh = (m==0)?H0:(m==1)?H1:H2;
    short* Wl = (m==0)?L0:(m==1)?L1:L2;
    const int gid = (blockIdx.x & 127)*256 + threadIdx.x;
    const int n  = gid & 511;
    const int kc = (gid >> 9) * 8;
    short hi[8], lo[8];
    #pragma unroll
    for (int j=0;j<8;j++) split2(W[(size_t)(kc+j)*512 + n], hi[j], lo[j]);
    *(short4*)&Wh[(size_t)n*512 + kc]     = make_short4(hi[0],hi[1],hi[2],hi[3]);
    *(short4*)&Wh[(size_t)n*512 + kc + 4] = make_short4(hi[4],hi[5],hi[6],hi[7]);
    *(short4*)&Wl[(size_t)n*512 + kc]     = make_short4(lo[0],lo[1],lo[2],lo[3]);
    *(short4*)&Wl[(size_t)n*512 + kc + 4] = make_short4(lo[4],lo[5],lo[6],lo[7]);
}

// ======================= fp32 -> single bf16 =======================
__global__ __launch_bounds__(256) void cvt_bf16(
    const float* __restrict__ X, short* __restrict__ Xb)
{
    const size_t i0 = ((size_t)blockIdx.x*256 + threadIdx.x)*8;
    float4 a = *(const float4*)(X+i0), bq = *(const float4*)(X+i0+4);
    float v[8] = {a.x,a.y,a.z,a.w,bq.x,bq.y,bq.z,bq.w};
    short o[8];
    #pragma unroll
    for (int j=0;j<8;j++) o[j] = (short)f2b(v[j]);
    *(short4*)(Xb+i0)   = make_short4(o[0],o[1],o[2],o[3]);
    *(short4*)(Xb+i0+4) = make_short4(o[4],o[5],o[6],o[7]);
}

// ======== x1 GEMM: 256 thr, 4 waves of 32x32, A/B single bf16, reg-prefetch ========
// OUT_MODE: 0=fp32, 3=bf16
template<int OUT_MODE, int RELU_OUT>
__global__ __launch_bounds__(256) void gemm1(
    const short* __restrict__ Ab, const short* __restrict__ Wb,
    const float* __restrict__ bias,
    float* __restrict__ Cf, short* __restrict__ Cb)
{
    __shared__ short As[64*LDK], Bs[64*LDK];
    const int t = threadIdx.x;
    const int row0 = blockIdx.y*64, col0 = blockIdx.x*64;
    const int lane = t & 63, w = t >> 6;
    const int m0 = (w>>1)*32, n0 = (w&1)*32;
    const int fl = lane & 15, quad = lane >> 4;
    const int s_row = t >> 2, s_k = (t & 3) * 8;

    f32x4 zero = {0.f,0.f,0.f,0.f};
    f32x4 acc[2][2];
    acc[0][0]=zero; acc[0][1]=zero; acc[1][0]=zero; acc[1][1]=zero;

    const size_t a_base = (size_t)(row0+s_row)*512 + s_k;
    const size_t b_base = (size_t)(col0+s_row)*512 + s_k;
    int4 ra = *(const int4*)(Ab + a_base);
    int4 rb = *(const int4*)(Wb + b_base);

    for (int k0 = 0; k0 < 512; k0 += 32) {
        *(int4*)&As[s_row*LDK + s_k] = ra;
        *(int4*)&Bs[s_row*LDK + s_k] = rb;
        __syncthreads();
        if (k0 + 32 < 512) {
            ra = *(const int4*)(Ab + a_base + k0 + 32);
            rb = *(const int4*)(Wb + b_base + k0 + 32);
        }
        bf16x8 fa[2], fb[2];
        #pragma unroll
        for (int i=0;i<2;i++) {
            fa[i] = *(const bf16x8*)&As[(m0 + i*16 + fl)*LDK + quad*8];
            fb[i] = *(const bf16x8*)&Bs[(n0 + i*16 + fl)*LDK + quad*8];
        }
        #pragma unroll
        for (int i=0;i<2;i++)
        #pragma unroll
        for (int j=0;j<2;j++)
            acc[i][j] = __builtin_amdgcn_mfma_f32_16x16x32_bf16(fa[i], fb[j], acc[i][j], 0,0,0);
        __syncthreads();
    }
    #pragma unroll
    for (int i=0;i<2;i++)
    #pragma unroll
    for (int j=0;j<2;j++) {
        const int col = col0 + n0 + j*16 + fl;
        const float bb = bias ? bias[col] : 0.f;
        #pragma unroll
        for (int r=0;r<4;r++) {
            const int row = row0 + m0 + i*16 + quad*4 + r;
            const size_t off = (size_t)row*512 + col;
            float v = acc[i][j][r] + bb;
            if (RELU_OUT) v = fmaxf(v,0.f);
            if (OUT_MODE == 0) Cf[off] = v;
            else               Cb[off] = (short)f2b(v);
        }
    }
}

// ======== fused pos GEMM (x1): A = relu(d@d1w+d1b), d1 resident in LDS ========
__global__ __launch_bounds__(256) void gemm_pos(
    const float* __restrict__ xyz_q, const float* __restrict__ axyz, const int* __restrict__ knn,
    const float* __restrict__ d1w, const float* __restrict__ d1b,
    const short* __restrict__ Wb, const float* __restrict__ bias,
    short* __restrict__ Cb, int qbase)
{
    __shared__ short As[64*LDK], Bs[64*LDK];
    __shared__ float sd1[4][512];
    __shared__ float sdx[64], sdy[64], sdz[64];
    const int t = threadIdx.x;
    const int row0 = blockIdx.y*64, col0 = blockIdx.x*64;
    const int lane = t & 63, w = t >> 6;
    const int m0 = (w>>1)*32, n0 = (w&1)*32;
    const int fl = lane & 15, quad = lane >> 4;
    const int s_row = t >> 2, s_k = (t & 3) * 8;
    for (int i=t;i<2048;i+=256) {
        int r = i >> 9, c = i & 511;
        sd1[r][c] = (r < 3) ? d1w[r*512 + c] : d1b[c];
    }
    if (t < 64) {
        int gr = qbase*8 + row0 + t;
        int b  = gr >> 15;
        int gq = gr >> 3;
        int idx = knn[gr];
        const float* qp = xyz_q + (size_t)gq*3;
        const float* ap = axyz + (size_t)(b*NA + idx)*3;
        sdx[t]=qp[0]-ap[0]; sdy[t]=qp[1]-ap[1]; sdz[t]=qp[2]-ap[2];
    }
    __syncthreads();
    const float dx = sdx[s_row], dy = sdy[s_row], dz = sdz[s_row];

    f32x4 zero = {0.f,0.f,0.f,0.f};
    f32x4 acc[2][2];
    acc[0][0]=zero; acc[0][1]=zero; acc[1][0]=zero; acc[1][1]=zero;

    const size_t b_base = (size_t)(col0+s_row)*512 + s_k;
    int4 rb = *(const int4*)(Wb + b_base);

    for (int k0 = 0; k0 < 512; k0 += 32) {
        {
            short o[8];
            #pragma unroll
            for (int j=0;j<8;j++) {
                int k = k0 + s_k + j;
                float v = fmaf(dx, sd1[0][k], fmaf(dy, sd1[1][k], fmaf(dz, sd1[2][k], sd1[3][k])));
                o[j] = (short)f2b(fmaxf(v, 0.f));
            }
            *(short4*)&As[s_row*LDK + s_k]     = make_short4(o[0],o[1],o[2],o[3]);
            *(short4*)&As[s_row*LDK + s_k + 4] = make_short4(o[4],o[5],o[6],o[7]);
        }
        *(int4*)&Bs[s_row*LDK + s_k] = rb;
        __syncthreads();
        if (k0 + 32 < 512) rb = *(const int4*)(Wb + b_base + k0 + 32);
        bf16x8 fa[2], fb[2];
        #pragma unroll
        for (int i=0;i<2;i++) {
            fa[i] = *(const bf16x8*)&As[(m0 + i*16 + fl)*LDK + quad*8];
            fb[i] = *(const bf16x8*)&Bs[(n0 + i*16 + fl)*LDK + quad*8];
        }
        #pragma unroll
        for (int i=0;i<2;i++)
        #pragma unroll
        for (int j=0;j<2;j++)
            acc[i][j] = __builtin_amdgcn_mfma_f32_16x16x32_bf16(fa[i], fb[j], acc[i][j], 0,0,0);
        __syncthreads();
    }
    #pragma unroll
    for (int i=0;i<2;i++)
    #pragma unroll
    for (int j=0;j<2;j++) {
        const int col = col0 + n0 + j*16 + fl;
        const float bb = bias[col];
        #pragma unroll
        for (int r=0;r<4;r++) {
            const int row = row0 + m0 + i*16 + quad*4 + r;
            Cb[(size_t)row*512 + col] = (short)f2b(acc[i][j][r] + bb);
        }
    }
}

// ======== fused g1 GEMM (x1): A = q_attn - k + pos, reg-prefetch all streams ========
__global__ __launch_bounds__(256) void gemm_g1(
    const float* __restrict__ q_attn, const float* __restrict__ kgv,
    const short* __restrict__ ak_bf, const short* __restrict__ pos_bf, const int* __restrict__ knn,
    const short* __restrict__ Wb, const float* __restrict__ bias,
    short* __restrict__ Cb, int qbase)
{
    __shared__ short As[64*LDK], Bs[64*LDK];
    __shared__ int s_aoff[64], s_poff[64];
    const int t = threadIdx.x;
    const int row0 = blockIdx.y*64, col0 = blockIdx.x*64;
    const int lane = t & 63, w = t >> 6;
    const int m0 = (w>>1)*32, n0 = (w&1)*32;
    const int fl = lane & 15, quad = lane >> 4;
    const int s_row = t >> 2, s_k = (t & 3) * 8;
    const int b = qbase >> 12;
    if (t < 64) {
        int g = row0 + t;
        int q = g / 9, n = g - q*9;
        if (n < 8) { s_aoff[t] = b*NA + knn[(size_t)(qbase + q)*8 + n]; s_poff[t] = q*8 + n; }
        else       { s_aoff[t] = -1; s_poff[t] = 0; }
    }
    __syncthreads();
    const int ao = s_aoff[s_row];
    const int po = s_poff[s_row];

    f32x4 zero = {0.f,0.f,0.f,0.f};
    f32x4 acc[2][2];
    acc[0][0]=zero; acc[0][1]=zero; acc[1][0]=zero; acc[1][1]=zero;

    const size_t b_base = (size_t)(col0+s_row)*512 + s_k;
    int4 rb = *(const int4*)(Wb + b_base);
    float4 qa0, qa1, gk0, gk1;
    ushort4 kv0, kv1, pv0, pv1;
    qa0 = ld4(q_attn + b*512 + s_k); qa1 = ld4(q_attn + b*512 + s_k + 4);
    if (ao >= 0) {
        kv0 = *(const ushort4*)(ak_bf + (size_t)ao*512 + s_k);
        kv1 = *(const ushort4*)(ak_bf + (size_t)ao*512 + s_k + 4);
        pv0 = *(const ushort4*)(pos_bf + (size_t)po*512 + s_k);
        pv1 = *(const ushort4*)(pos_bf + (size_t)po*512 + s_k + 4);
    } else {
        gk0 = ld4(kgv + b*512 + s_k); gk1 = ld4(kgv + b*512 + s_k + 4);
    }

    for (int k0 = 0; k0 < 512; k0 += 32) {
        {
            short o[8];
            if (ao >= 0) {
                o[0]=(short)f2b(qa0.x - b2f(kv0.x) + b2f(pv0.x));
                o[1]=(short)f2b(qa0.y - b2f(kv0.y) + b2f(pv0.y));
                o[2]=(short)f2b(qa0.z - b2f(kv0.z) + b2f(pv0.z));
                o[3]=(short)f2b(qa0.w - b2f(kv0.w) + b2f(pv0.w));
                o[4]=(short)f2b(qa1.x - b2f(kv1.x) + b2f(pv1.x));
                o[5]=(short)f2b(qa1.y - b2f(kv1.y) + b2f(pv1.y));
                o[6]=(short)f2b(qa1.z - b2f(kv1.z) + b2f(pv1.z));
                o[7]=(short)f2b(qa1.w - b2f(kv1.w) + b2f(pv1.w));
            } else {
                o[0]=(short)f2b(qa0.x - gk0.x); o[1]=(short)f2b(qa0.y - gk0.y);
                o[2]=(short)f2b(qa0.z - gk0.z); o[3]=(short)f2b(qa0.w - gk0.w);
                o[4]=(short)f2b(qa1.x - gk1.x); o[5]=(short)f2b(qa1.y - gk1.y);
                o[6]=(short)f2b(qa1.z - gk1.z); o[7]=(short)f2b(qa1.w - gk1.w);
            }
            *(short4*)&As[s_row*LDK + s_k]     = make_short4(o[0],o[1],o[2],o[3]);
            *(short4*)&As[s_row*LDK + s_k + 4] = make_short4(o[4],o[5],o[6],o[7]);
        }
        *(int4*)&Bs[s_row*LDK + s_k] = rb;
        __syncthreads();
        if (k0 + 32 < 512) {
            const int k = k0 + 32 + s_k;
            rb = *(const int4*)(Wb + b_base + k0 + 32);
            qa0 = ld4(q_attn + b*512 + k); qa1 = ld4(q_attn + b*512 + k + 4);
            if (ao >= 0) {
                kv0 = *(const ushort4*)(ak_bf + (size_t)ao*512 + k);
                kv1 = *(const ushort4*)(ak_bf + (size_t)ao*512 + k + 4);
                pv0 = *(const ushort4*)(pos_bf + (size_t)po*512 + k);
                pv1 = *(const ushort4*)(pos_bf + (size_t)po*512 + k + 4);
            } else {
                gk0 = ld4(kgv + b*512 + k); gk1 = ld4(kgv + b*512 + k + 4);
            }
        }
        bf16x8 fa[2], fb[2];
        #pragma unroll
        for (int i=0;i<2;i++) {
            fa[i] = *(const bf16x8*)&As[(m0 + i*16 + fl)*LDK + quad*8];
            fb[i] = *(const bf16x8*)&Bs[(n0 + i*16 + fl)*LDK + quad*8];
        }
        #pragma unroll
        for (int i=0;i<2;i++)
        #pragma unroll
        for (int j=0;j<2;j++)
            acc[i][j] = __builtin_amdgcn_mfma_f32_16x16x32_bf16(fa[i], fb[j], acc[i][j], 0,0,0);
        __syncthreads();
    }
    #pragma unroll
    for (int i=0;i<2;i++)
    #pragma unroll
    for (int j=0;j<2;j++) {
        const int col = col0 + n0 + j*16 + fl;
        const float bb = bias[col];
        #pragma unroll
        for (int r=0;r<4;r++) {
            const int row = row0 + m0 + i*16 + quad*4 + r;
            Cb[(size_t)row*512 + col] = (short)f2b(fmaxf(acc[i][j][r] + bb, 0.f));
        }
    }
}

// ======== x3 decoder GEMM: 256 thr, 4 waves of 32x32, A h/l + B h/l, reg-prefetch ========
// OUT_MODE: 0=fp32; 1=split bf16; 2=fp32 + split(relu(v))
template<int OUT_MODE, int RELU_OUT, int HAS_ADD>
__global__ __launch_bounds__(256) void gemm3(
    const short* __restrict__ Ah, const short* __restrict__ Al,
    const short* __restrict__ Wh, const short* __restrict__ Wl,
    const float* __restrict__ bias, const float* __restrict__ addend,
    float* __restrict__ Cf, short* __restrict__ Ch, short* __restrict__ Cl)
{
    __shared__ short As_h[64*LDK], As_l[64*LDK], Bs_h[64*LDK], Bs_l[64*LDK];
    const int t = threadIdx.x;
    const int row0 = blockIdx.y*64, col0 = blockIdx.x*64;
    const int lane = t & 63, w = t >> 6;
    const int m0 = (w>>1)*32, n0 = (w&1)*32;
    const int fl = lane & 15, quad = lane >> 4;
    const int s_row = t >> 2, s_k = (t & 3) * 8;

    f32x4 zero = {0.f,0.f,0.f,0.f};
    f32x4 acc[2][2];
    acc[0][0]=zero; acc[0][1]=zero; acc[1][0]=zero; acc[1][1]=zero;

    const size_t a_base = (size_t)(row0+s_row)*512 + s_k;
    const size_t b_base = (size_t)(col0+s_row)*512 + s_k;
    int4 rah = *(const int4*)(Ah + a_base);
    int4 ral = *(const int4*)(Al + a_base);
    int4 rbh = *(const int4*)(Wh + b_base);
    int4 rbl = *(const int4*)(Wl + b_base);

    for (int k0 = 0; k0 < 512; k0 += 32) {
        *(int4*)&As_h[s_row*LDK + s_k] = rah;
        *(int4*)&As_l[s_row*LDK + s_k] = ral;
        *(int4*)&Bs_h[s_row*LDK + s_k] = rbh;
        *(int4*)&Bs_l[s_row*LDK + s_k] = rbl;
        __syncthreads();
        if (k0 + 32 < 512) {
            rah = *(const int4*)(Ah + a_base + k0 + 32);
            ral = *(const int4*)(Al + a_base + k0 + 32);
            rbh = *(const int4*)(Wh + b_base + k0 + 32);
            rbl = *(const int4*)(Wl + b_base + k0 + 32);
        }
        bf16x8 fah[2], fal[2], fbh[2], fbl[2];
        #pragma unroll
        for (int i=0;i<2;i++) {
            fah[i] = *(const bf16x8*)&As_h[(m0 + i*16 + fl)*LDK + quad*8];
            fal[i] = *(const bf16x8*)&As_l[(m0 + i*16 + fl)*LDK + quad*8];
            fbh[i] = *(const bf16x8*)&Bs_h[(n0 + i*16 + fl)*LDK + quad*8];
            fbl[i] = *(const bf16x8*)&Bs_l[(n0 + i*16 + fl)*LDK + quad*8];
        }
        #pragma unroll
        for (int i=0;i<2;i++)
        #pragma unroll
        for (int j=0;j<2;j++)
            acc[i][j] = __builtin_amdgcn_mfma_f32_16x16x32_bf16(fah[i], fbh[j], acc[i][j], 0,0,0);
        #pragma unroll
        for (int i=0;i<2;i++)
        #pragma unroll
        for (int j=0;j<2;j++)
            acc[i][j] = __builtin_amdgcn_mfma_f32_16x16x32_bf16(fah[i], fbl[j], acc[i][j], 0,0,0);
        #pragma unroll
        for (int i=0;i<2;i++)
        #pragma unroll
        for (int j=0;j<2;j++)
            acc[i][j] = __builtin_amdgcn_mfma_f32_16x16x32_bf16(fal[i], fbh[j], acc[i][j], 0,0,0);
        __syncthreads();
    }
    #pragma unroll
    for (int i=0;i<2;i++)
    #pragma unroll
    for (int j=0;j<2;j++) {
        const int col = col0 + n0 + j*16 + fl;
        const float bb = bias ? bias[col] : 0.f;
        #pragma unroll
        for (int r=0;r<4;r++) {
            const int row = row0 + m0 + i*16 + quad*4 + r;
            const size_t off = (size_t)row*512 + col;
            float v = acc[i][j][r] + bb;
            if (HAS_ADD) v += addend[off];
            if (OUT_MODE == 0) {
                if (RELU_OUT) v = fmaxf(v,0.f);
                Cf[off] = v;
            } else if (OUT_MODE == 1) {
                if (RELU_OUT) v = fmaxf(v,0.f);
                short h,l; split2(v,h,l); Ch[off]=h; Cl[off]=l;
            } else {
                Cf[off] = v;
                short h,l; split2(fmaxf(v,0.f),h,l); Ch[off]=h; Cl[off]=l;
            }
        }
    }
}

// ======================= softmax + aggregation =======================
__global__ __launch_bounds__(256) void softmax_agg(
    const short* __restrict__ attn_preb, const short* __restrict__ pos_bf,
    const short* __restrict__ av_bf, const float* __restrict__ vgv,
    const int* __restrict__ knn, short* __restrict__ lath, short* __restrict__ latl, int qbase)
{
    __shared__ int sk[8];
    const int q = blockIdx.x;
    const int gq = qbase + q;
    const int b = qbase >> 12;
    const int t = threadIdx.x;
    if (t < 8) sk[t] = knn[(size_t)gq*8 + t];
    __syncthreads();
    for (int c = t; c < 512; c += 256) {
        float p[9];
        #pragma unroll
        for (int n=0;n<9;n++) p[n] = b2f((unsigned short)attn_preb[(size_t)(q*9+n)*512 + c]);
        float m = p[0];
        #pragma unroll
        for (int n=1;n<9;n++) m = fmaxf(m, p[n]);
        float e[9], s = 0.f;
        #pragma unroll
        for (int n=0;n<9;n++){ e[n] = expf(p[n]-m); s += e[n]; }
        const float inv = 1.0f / s;
        float acc = 0.f;
        #pragma unroll
        for (int n=0;n<8;n++) {
            float vv = b2f((unsigned short)av_bf[(size_t)(b*NA + sk[n])*512 + c])
                     + b2f((unsigned short)pos_bf[(size_t)(q*8+n)*512 + c]);
            acc = fmaf(e[n]*inv, vv, acc);
        }
        acc = fmaf(e[8]*inv, vgv[b*512 + c], acc);
        short h,l; split2(acc,h,l);
        lath[(size_t)gq*512 + c] = h; latl[(size_t)gq*512 + c] = l;
    }
}

// ======================= PE + first decoder layer =======================
__global__ __launch_bounds__(256) void pe_fc(
    const float* __restrict__ xyz_q, const float* __restrict__ fw, const float* __restrict__ fb,
    float* __restrict__ net)
{
    __shared__ float spe[16*60];
    const int t = threadIdx.x;
    const int q0 = blockIdx.x * 16;
    for (int i=t;i<960;i+=256) {
        int ql = i/60, j = i - ql*60;
        int l = j/6; int r6 = j - l*6; int s = r6/3; int d = r6 - s*3;
        float pv = xyz_q[(size_t)(q0+ql)*3 + d];
        float a = pv * (3.14159265358979323846f * (float)(1<<l));
        spe[ql*60+j] = (s==0) ? sinf(a) : cosf(a);
    }
    __syncthreads();
    float acc0[16], acc1[16];
    #pragma unroll
    for (int ql=0;ql<16;ql++){ acc0[ql]=0.f; acc1[ql]=0.f; }
    const int c0 = t, c1 = t + 256;
    for (int k=0;k<60;k++) {
        float w0 = fw[k*512 + c0];
        float w1 = fw[k*512 + c1];
        #pragma unroll
        for (int ql=0;ql<16;ql++) {
            float pv = spe[ql*60+k];
            acc0[ql] = fmaf(pv, w0, acc0[ql]);
            acc1[ql] = fmaf(pv, w1, acc1[ql]);
        }
    }
    const float b0v = fb[c0], b1v = fb[c1];
    #pragma unroll
    for (int ql=0;ql<16;ql++) {
        net[(size_t)(q0+ql)*512 + c0] = acc0[ql] + b0v;
        net[(size_t)(q0+ql)*512 + c1] = acc1[ql] + b1v;
    }
}

// ======================= launch =======================
extern "C" void kernel_launch(void* const* d_in, const int* in_sizes, int n_in,
                              void* d_out, int out_size, void* d_ws, size_t ws_size,
                              hipStream_t stream) {
    const float* xyz_q  = (const float*)d_in[0];
    const float* gf     = (const float*)d_in[1];
    const float* axyz   = (const float*)d_in[2];
    const float* afeat  = (const float*)d_in[3];
    const float* w_qs   = (const float*)d_in[4];
    const float* w_ks   = (const float*)d_in[5];
    const float* w_vs   = (const float*)d_in[6];
    const float* w_kg   = (const float*)d_in[7];
    const float* w_vg   = (const float*)d_in[8];
    const float* d1_w   = (const float*)d_in[9];
    const float* d1_b   = (const float*)d_in[10];
    const float* d2_w   = (const float*)d_in[11];
    const float* d2_b   = (const float*)d_in[12];
    const float* g1_w   = (const float*)d_in[13];
    const float* g1_b   = (const float*)d_in[14];
    const float* g2_w   = (const float*)d_in[15];
    const float* g2_b   = (const float*)d_in[16];
    const float* fc_p_w = (const float*)d_in[17];
    const float* fc_p_b = (const float*)d_in[18];
    const float* fc_c_w = (const float*)d_in[19];
    const float* fc_c_b = (const float*)d_in[20];
    const float* blk0_w = (const float*)d_in[21];
    const float* blk0_b = (const float*)d_in[22];
    const float* blk1_w = (const float*)d_in[23];
    const float* blk1_b = (const float*)d_in[24];
    float* out = (float*)d_out;

    const size_t MB = 1u<<20;
    char* base = (char*)d_ws;
    // ---- persistent (21 MB) ----
    float* q_attn = (float*)base;
    float* kgv    = q_attn + 1024;
    float* vgv    = kgv + 1024;
    int*   knn    = (int*)(base + 16*1024);
    short* wksb = (short*)(base + 1*MB);        // attention weights, 0.5 MB each
    short* wvsb = wksb + 262144;
    short* wd2b = wvsb + 262144;
    short* wg1b = wd2b + 262144;
    short* wg2b = wg1b + 262144;                // ends base+3.5 MB
    // decoder slots alias the (then-dead) attention weight region: 6 x 0.5 MB
    short* dch = (short*)(base + 1*MB);         short* dcl = dch + 262144;
    short* d0h = dcl + 262144;                  short* d0l = d0h + 262144;
    short* d1h = d0l + 262144;                  short* d1l = d1h + 262144;  // ends base+4 MB
    short* lath = (short*)(base + 5*MB);
    short* latl = (short*)(base + 13*MB);
    // ---- transient T (34 MB): total 55 MB ----
    char* T = base + 21*MB;
    short* ak_bf = (short*)T;                    // 4 MB
    short* av_bf = (short*)(T + 4*MB);           // 4 MB
    short* posb  = (short*)(T + 8*MB);           // 8 MB
    short* yb    = (short*)(T + 16*MB);          // 9 MB
    short* attn_preb = (short*)(T + 25*MB);      // 9 MB
    short* af_bf = (short*)(T + 8*MB);           // 4 MB (phase A overlay)
    short* nrh = (short*)T;            short* nrl = (short*)(T + 8*MB);
    short* hdh = (short*)(T + 16*MB);  short* hdl = (short*)(T + 24*MB);
    if ((size_t)(55*MB) > ws_size) return;

    proj_small<<<dim3(6), dim3(256), 0, stream>>>(gf, w_qs, w_kg, w_vg, q_attn, kgv, vgv);
    knn_kernel<<<dim3(1024), dim3(256), 0, stream>>>(xyz_q, axyz, knn);

    cvt_bf16<<<dim3(1024), dim3(256), 0, stream>>>(afeat, af_bf);
    prep_w5<<<dim3(640), dim3(256), 0, stream>>>(w_ks, w_vs, d2_w, g1_w, g2_w,
                                                 wksb, wvsb, wd2b, wg1b, wg2b);
    gemm1<3,0><<<dim3(8,64), dim3(256), 0, stream>>>(af_bf, wksb, nullptr, nullptr, ak_bf);
    gemm1<3,0><<<dim3(8,64), dim3(256), 0, stream>>>(af_bf, wvsb, nullptr, nullptr, av_bf);

    for (int qbase = 0; qbase < B*NQ; qbase += CH) {
        gemm_pos<<<dim3(8, CH*8/64), dim3(256), 0, stream>>>(xyz_q, axyz, knn, d1_w, d1_b, wd2b, d2_b, posb, qbase);
        gemm_g1<<<dim3(8, CH*9/64), dim3(256), 0, stream>>>(q_attn, kgv, ak_bf, posb, knn, wg1b, g1_b, yb, qbase);
        gemm1<3,0><<<dim3(8, CH*9/64), dim3(256), 0, stream>>>(yb, wg2b, g2_b, nullptr, attn_preb);
        softmax_agg<<<dim3(CH), dim3(256), 0, stream>>>(attn_preb, posb, av_bf, vgv, knn, lath, latl, qbase);
    }

    pe_fc<<<dim3(512), dim3(256), 0, stream>>>(xyz_q, fc_p_w, fc_p_b, out);
    for (int i=0;i<5;i++) {
        const float* cw  = fc_c_w + (size_t)i*512*512;
        const float* cb  = fc_c_b + (size_t)i*512;
        const float* b0w = blk0_w + (size_t)i*512*512;
        const float* b0b = blk0_b + (size_t)i*512;
        const float* b1w = blk1_w + (size_t)i*512*512;
        const float* b1b = blk1_b + (size_t)i*512;
        prep_w3<<<dim3(384), dim3(256), 0, stream>>>(cw, b0w, b1w, dch, dcl, d0h, d0l, d1h, d1l);
        gemm3<2,0,1><<<dim3(8,128), dim3(256), 0, stream>>>(lath, latl, dch, dcl, cb, out, out, nrh, nrl);
        gemm3<1,1,0><<<dim3(8,128), dim3(256), 0, stream>>>(nrh, nrl, d0h, d0l, b0b, nullptr, nullptr, hdh, hdl);
        gemm3<0,0,1><<<dim3(8,128), dim3(256), 0, stream>>>(hdh, hdl, d1h, d1l, b1b, out, out, nullptr, nullptr);
    }
}